// Round 10
// baseline (4895.374 us; speedup 1.0000x reference)
//
#include <hip/hip_runtime.h>

typedef short bf16x8 __attribute__((ext_vector_type(8)));
typedef float f32x4 __attribute__((ext_vector_type(4)));

#define B_ 256
#define T_ 1024
#define H_ 512
#define E_ 256
#define O_ 256
#define V_ 256

// Prepped operands in device globals: graph-safe, rewritten every launch.
__device__ __align__(16) unsigned short g_P[V_ * H_];     // P = emb@Wx^T + b, bf16 (256 KB)
__device__ __align__(16) unsigned short g_Whf[H_ * H_];   // Wh in MFMA B-frag layout (512 KB)
__device__ __align__(16) unsigned short g_Wdf[O_ * H_];   // Wd in MFMA B-frag layout (256 KB)

// Cross-block h exchange: ROW-MAJOR packed-u32 bf16 pairs — byte image == the
// row-major bf16 h matrix (gather -> LDS image -> swizzled A-frag reads).
__device__ __align__(16) unsigned g_ex[2][16][16 * 256];  // 2 x 16 groups x 16 KB
__device__ unsigned g_flag[16][64];                       // flag line per supergroup

__device__ __forceinline__ unsigned short f2bf(float f) {
    union { float f; unsigned int u; } v; v.f = f;
    unsigned int r = v.u + 0x7fffu + ((v.u >> 16) & 1u);   // RNE
    return (unsigned short)(r >> 16);
}
__device__ __forceinline__ float bf2f(unsigned short s) {
    union { unsigned int u; float f; } v; v.u = ((unsigned int)s) << 16;
    return v.f;
}
#define TANH_(v_) (1.f - __fdividef(2.f, __expf((v_) + (v_)) + 1.f))

// ---------------- K1a: P = b + emb @ Wx^T (bf16); zero flags ----------------
__global__ void k_embWx(const float* __restrict__ emb, const float* __restrict__ W,
                        const float* __restrict__ bb) {
    if (blockIdx.x == 0)
        for (int i = threadIdx.x; i < 16 * 64; i += 256) ((unsigned*)g_flag)[i] = 0;
    __shared__ float e[E_];
    int v = blockIdx.x;
    e[threadIdx.x] = emb[(size_t)v * E_ + threadIdx.x];
    __syncthreads();
#pragma unroll
    for (int rep = 0; rep < 2; rep++) {
        int n = threadIdx.x + rep * 256;
        const float4* wr4 = (const float4*)(W + (size_t)n * (E_ + H_));
        float s = bb[n];
        for (int k = 0; k < E_ / 4; k++) {
            float4 wv = wr4[k];
            s += e[4*k] * wv.x + e[4*k+1] * wv.y + e[4*k+2] * wv.z + e[4*k+3] * wv.w;
        }
        g_P[v * H_ + n] = f2bf(s);
    }
}

// ---------------- K1b/K1c: weight -> MFMA B-fragment layout (bf16) ----------------
__global__ void k_fragWh(const float* __restrict__ W) {
    int gid = blockIdx.x * blockDim.x + threadIdx.x;
    int l = gid & 63, tile = gid >> 6;
    int kt = tile & 15, nt = tile >> 4;
    int n = nt * 16 + (l & 15), k0 = kt * 32 + (l >> 4) * 8;
    const float* src = W + (size_t)n * (E_ + H_) + E_ + k0;
#pragma unroll
    for (int j = 0; j < 8; j++) g_Whf[(size_t)gid * 8 + j] = f2bf(src[j]);
}
__global__ void k_fragWd(const float* __restrict__ Wd) {
    int gid = blockIdx.x * blockDim.x + threadIdx.x;
    int l = gid & 63, tile = gid >> 6;
    int kt = tile & 15, nt = tile >> 4;
    int n = nt * 16 + (l & 15), k0 = kt * 32 + (l >> 4) * 8;
    const float* src = Wd + (size_t)n * H_ + k0;
#pragma unroll
    for (int j = 0; j < 8; j++) g_Wdf[(size_t)gid * 8 + j] = f2bf(src[j]);
}

// ---------------- K2: recurrence — DUAL-GROUP per block (amortized L3 sync) ----------------
// 32 blocks = 8 supergroups x 4 quarters; block handles row-groups gA=s, gB=s+8
// (SAME Wh frags -> breg shared, 64 VGPRs; total ~116 < the hard 128 ceiling).
// R7 vs R9 identical times proved the step cost is the serial L3 RT chain
// (ex-ack -> flag -> poll -> gather ~8000cy), which is LATENCY not bandwidth:
// so batch 2 independent groups through ONE chain per super-step -> ~2x.
// Per super-step: MFMA+tanh A,B -> ex stores A,B -> u prefetch A,B -> vmcnt(8)
// [all 8 ex instrs retired, 8 u loads fly] -> barrier -> flag (plain store) ->
// poll 1 line -> gather A+B (one RT) -> ds_write images -> designated block
// q==(t&3) writes hs[:,t] COALESCED from gathered regs (kills R9's scattered
// 2B stores + 3x write amplification) -> barrier.
__global__ void __launch_bounds__(512) k_rnn(const int* __restrict__ x,
                                             const float* __restrict__ h0,
                                             float* __restrict__ out) {
    __shared__ __align__(16) unsigned short lds_h[2][16 * 512];   // images for gA, gB
    const int tid = threadIdx.x;
    const int w = tid >> 6, l = tid & 63;
    const int hi = l >> 4, lo = l & 15;
    const int s = blockIdx.x >> 2, q = blockIdx.x & 3;
    const int gA = s, gB = s + 8;
    const int r0A = gA * 16, r0B = gB * 16;
    const int nt = q * 8 + w;
    const int n = nt * 16 + lo;
    const int sw = (lo & 7) << 4;               // A-read swizzle

    // pinned Wh B-frags: 16 x 4 = 64 VGPRs (shared by both groups)
    bf16x8 breg[16];
#pragma unroll
    for (int kt = 0; kt < 16; kt++)
        breg[kt] = *(const bf16x8*)(g_Whf + (nt * 16 + kt) * 512 + l * 8);

    // stage h0 -> both LDS images (swizzled)
    {
        const int row = tid >> 5;
        const int cb = (tid & 31) * 32;
        const int gsw = (row & 7) << 4;
#pragma unroll
        for (int grp = 0; grp < 2; grp++) {
            const int r0g = grp ? r0B : r0A;
            const float* hp = h0 + (size_t)(r0g + row) * H_ + (tid & 31) * 16;
            unsigned pk[8];
#pragma unroll
            for (int i = 0; i < 8; i++)
                pk[i] = (unsigned)f2bf(hp[2 * i]) | ((unsigned)f2bf(hp[2 * i + 1]) << 16);
            char* hw = (char*)lds_h[grp] + row * 1024;
            *(uint4*)(hw + ((cb)      ^ gsw)) = make_uint4(pk[0], pk[1], pk[2], pk[3]);
            *(uint4*)(hw + ((cb + 16) ^ gsw)) = make_uint4(pk[4], pk[5], pk[6], pk[7]);
        }
    }
    __syncthreads();

    const int xrA = r0A + hi * 4, xrB = r0B + hi * 4;   // each thread's 4 rows per group
    unsigned uA0 = g_P[x[(xrA + 0) * T_] * H_ + n];
    unsigned uA1 = g_P[x[(xrA + 1) * T_] * H_ + n];
    unsigned uA2 = g_P[x[(xrA + 2) * T_] * H_ + n];
    unsigned uA3 = g_P[x[(xrA + 3) * T_] * H_ + n];
    unsigned uB0 = g_P[x[(xrB + 0) * T_] * H_ + n];
    unsigned uB1 = g_P[x[(xrB + 1) * T_] * H_ + n];
    unsigned uB2 = g_P[x[(xrB + 2) * T_] * H_ + n];
    unsigned uB3 = g_P[x[(xrB + 3) * T_] * H_ + n];

    unsigned short* hs = (unsigned short*)out;   // hs bf16 in-place in d_out
    const unsigned long long* flq = (const unsigned long long*)&g_flag[s][0];
    unsigned mA0 = 0, mA1 = 0, mA2 = 0, mA3 = 0;
    unsigned mB0 = 0, mB1 = 0, mB2 = 0, mB3 = 0;

#pragma unroll 1
    for (unsigned t = 0; t < T_; t++) {
        const int tn = (t < T_ - 1) ? (int)(t + 1) : (int)t;
        const int xnA0 = x[(xrA + 0) * T_ + tn], xnA1 = x[(xrA + 1) * T_ + tn];
        const int xnA2 = x[(xrA + 2) * T_ + tn], xnA3 = x[(xrA + 3) * T_ + tn];
        const int xnB0 = x[(xrB + 0) * T_ + tn], xnB1 = x[(xrB + 1) * T_ + tn];
        const int xnB2 = x[(xrB + 2) * T_ + tn], xnB3 = x[(xrB + 3) * T_ + tn];

        // ---- group A: acc = hA @ Wh^T (+uA via C-init) ----
        {
            f32x4 aca = {bf2f((unsigned short)uA0), bf2f((unsigned short)uA1),
                         bf2f((unsigned short)uA2), bf2f((unsigned short)uA3)};
            f32x4 acb = {0.f, 0.f, 0.f, 0.f};
            const char* hb = (const char*)lds_h[0];
#pragma unroll
            for (int kt = 0; kt < 16; kt += 2) {
                bf16x8 a0 = *(const bf16x8*)(hb + lo * 1024 + ((kt * 64 + hi * 16) ^ sw));
                bf16x8 a1 = *(const bf16x8*)(hb + lo * 1024 + (((kt + 1) * 64 + hi * 16) ^ sw));
                aca = __builtin_amdgcn_mfma_f32_16x16x32_bf16(a0, breg[kt],     aca, 0, 0, 0);
                acb = __builtin_amdgcn_mfma_f32_16x16x32_bf16(a1, breg[kt + 1], acb, 0, 0, 0);
            }
            mA0 = f2bf(TANH_(aca[0] + acb[0]));
            mA1 = f2bf(TANH_(aca[1] + acb[1]));
            mA2 = f2bf(TANH_(aca[2] + acb[2]));
            mA3 = f2bf(TANH_(aca[3] + acb[3]));
        }
        // ---- group B ----
        {
            f32x4 aca = {bf2f((unsigned short)uB0), bf2f((unsigned short)uB1),
                         bf2f((unsigned short)uB2), bf2f((unsigned short)uB3)};
            f32x4 acb = {0.f, 0.f, 0.f, 0.f};
            const char* hb = (const char*)lds_h[1];
#pragma unroll
            for (int kt = 0; kt < 16; kt += 2) {
                bf16x8 a0 = *(const bf16x8*)(hb + lo * 1024 + ((kt * 64 + hi * 16) ^ sw));
                bf16x8 a1 = *(const bf16x8*)(hb + lo * 1024 + (((kt + 1) * 64 + hi * 16) ^ sw));
                aca = __builtin_amdgcn_mfma_f32_16x16x32_bf16(a0, breg[kt],     aca, 0, 0, 0);
                acb = __builtin_amdgcn_mfma_f32_16x16x32_bf16(a1, breg[kt + 1], acb, 0, 0, 0);
            }
            mB0 = f2bf(TANH_(aca[0] + acb[0]));
            mB1 = f2bf(TANH_(aca[1] + acb[1]));
            mB2 = f2bf(TANH_(aca[2] + acb[2]));
            mB3 = f2bf(TANH_(aca[3] + acb[3]));
        }

        if (t < T_ - 1) {
            // pack col pairs + EX stores: A then B (4 store instrs/group, half-exec)
            __builtin_amdgcn_sched_barrier(0);
            {
                unsigned b0 = ((unsigned)__shfl_xor((int)mA0, 1)) & 0xffffu;
                unsigned b1 = ((unsigned)__shfl_xor((int)mA1, 1)) & 0xffffu;
                unsigned b2 = ((unsigned)__shfl_xor((int)mA2, 1)) & 0xffffu;
                unsigned b3 = ((unsigned)__shfl_xor((int)mA3, 1)) & 0xffffu;
                unsigned pk0, pk1, pk2, pk3;
                if (lo & 1) { pk0 = b0 | (mA0 << 16); pk1 = b1 | (mA1 << 16);
                              pk2 = b2 | (mA2 << 16); pk3 = b3 | (mA3 << 16); }
                else        { pk0 = mA0 | (b0 << 16); pk1 = mA1 | (b1 << 16);
                              pk2 = mA2 | (b2 << 16); pk3 = mA3 | (b3 << 16); }
                unsigned* exw = &g_ex[(t + 1) & 1][gA][0] + (n >> 1);
                if (!(lo & 1)) {
                    __hip_atomic_store(exw + (hi * 4 + 0) * 256, pk0, __ATOMIC_RELAXED, __HIP_MEMORY_SCOPE_AGENT);
                    __hip_atomic_store(exw + (hi * 4 + 1) * 256, pk1, __ATOMIC_RELAXED, __HIP_MEMORY_SCOPE_AGENT);
                } else {
                    __hip_atomic_store(exw + (hi * 4 + 2) * 256, pk2, __ATOMIC_RELAXED, __HIP_MEMORY_SCOPE_AGENT);
                    __hip_atomic_store(exw + (hi * 4 + 3) * 256, pk3, __ATOMIC_RELAXED, __HIP_MEMORY_SCOPE_AGENT);
                }
            }
            {
                unsigned b0 = ((unsigned)__shfl_xor((int)mB0, 1)) & 0xffffu;
                unsigned b1 = ((unsigned)__shfl_xor((int)mB1, 1)) & 0xffffu;
                unsigned b2 = ((unsigned)__shfl_xor((int)mB2, 1)) & 0xffffu;
                unsigned b3 = ((unsigned)__shfl_xor((int)mB3, 1)) & 0xffffu;
                unsigned pk0, pk1, pk2, pk3;
                if (lo & 1) { pk0 = b0 | (mB0 << 16); pk1 = b1 | (mB1 << 16);
                              pk2 = b2 | (mB2 << 16); pk3 = b3 | (mB3 << 16); }
                else        { pk0 = mB0 | (b0 << 16); pk1 = mB1 | (b1 << 16);
                              pk2 = mB2 | (b2 << 16); pk3 = mB3 | (b3 << 16); }
                unsigned* exw = &g_ex[(t + 1) & 1][gB][0] + (n >> 1);
                if (!(lo & 1)) {
                    __hip_atomic_store(exw + (hi * 4 + 0) * 256, pk0, __ATOMIC_RELAXED, __HIP_MEMORY_SCOPE_AGENT);
                    __hip_atomic_store(exw + (hi * 4 + 1) * 256, pk1, __ATOMIC_RELAXED, __HIP_MEMORY_SCOPE_AGENT);
                } else {
                    __hip_atomic_store(exw + (hi * 4 + 2) * 256, pk2, __ATOMIC_RELAXED, __HIP_MEMORY_SCOPE_AGENT);
                    __hip_atomic_store(exw + (hi * 4 + 3) * 256, pk3, __ATOMIC_RELAXED, __HIP_MEMORY_SCOPE_AGENT);
                }
            }
            __builtin_amdgcn_sched_barrier(0);
            // u(t+1) prefetch AFTER ex stores (so vmcnt(8) retires ex, leaves u flying)
            uA0 = g_P[xnA0 * H_ + n]; uA1 = g_P[xnA1 * H_ + n];
            uA2 = g_P[xnA2 * H_ + n]; uA3 = g_P[xnA3 * H_ + n];
            uB0 = g_P[xnB0 * H_ + n]; uB1 = g_P[xnB1 * H_ + n];
            uB2 = g_P[xnB2 * H_ + n]; uB3 = g_P[xnB3 * H_ + n];
            __builtin_amdgcn_sched_barrier(0);
            asm volatile("s_waitcnt vmcnt(8)" ::: "memory");   // 8 ex instrs retired
            __builtin_amdgcn_s_barrier();
            if (tid == 0)
                __hip_atomic_store(&g_flag[s][q], t + 1, __ATOMIC_RELAXED, __HIP_MEMORY_SCOPE_AGENT);

            // poll: all 4 quarters posted step t+1 for BOTH groups (one 16-B line)
            for (;;) {
                unsigned long long f0 = __hip_atomic_load(flq,     __ATOMIC_RELAXED, __HIP_MEMORY_SCOPE_AGENT);
                unsigned long long f1 = __hip_atomic_load(flq + 1, __ATOMIC_RELAXED, __HIP_MEMORY_SCOPE_AGENT);
                unsigned a = (unsigned)f0, b = (unsigned)(f0 >> 32);
                unsigned c = (unsigned)f1, d = (unsigned)(f1 >> 32);
                unsigned m = a < b ? a : b, m2 = c < d ? c : d;
                if ((m < m2 ? m : m2) > t) break;
                __builtin_amdgcn_s_sleep(1);
            }
            __builtin_amdgcn_sched_barrier(0);

            // gather both groups (one pipelined L3 RT), build LDS images,
            // designated block writes hs[:,t] coalesced from the same registers
            {
                const unsigned long long* exqA =
                    (const unsigned long long*)&g_ex[(t + 1) & 1][gA][0] + tid * 4;
                const unsigned long long* exqB =
                    (const unsigned long long*)&g_ex[(t + 1) & 1][gB][0] + tid * 4;
                unsigned long long a0q = __hip_atomic_load(exqA + 0, __ATOMIC_RELAXED, __HIP_MEMORY_SCOPE_AGENT);
                unsigned long long a1q = __hip_atomic_load(exqA + 1, __ATOMIC_RELAXED, __HIP_MEMORY_SCOPE_AGENT);
                unsigned long long a2q = __hip_atomic_load(exqA + 2, __ATOMIC_RELAXED, __HIP_MEMORY_SCOPE_AGENT);
                unsigned long long a3q = __hip_atomic_load(exqA + 3, __ATOMIC_RELAXED, __HIP_MEMORY_SCOPE_AGENT);
                unsigned long long b0q = __hip_atomic_load(exqB + 0, __ATOMIC_RELAXED, __HIP_MEMORY_SCOPE_AGENT);
                unsigned long long b1q = __hip_atomic_load(exqB + 1, __ATOMIC_RELAXED, __HIP_MEMORY_SCOPE_AGENT);
                unsigned long long b2q = __hip_atomic_load(exqB + 2, __ATOMIC_RELAXED, __HIP_MEMORY_SCOPE_AGENT);
                unsigned long long b3q = __hip_atomic_load(exqB + 3, __ATOMIC_RELAXED, __HIP_MEMORY_SCOPE_AGENT);
                const int grow = tid >> 5;
                const int gcb = (tid & 31) * 32;
                const int gsw = (grow & 7) << 4;
                union { unsigned long long qq[2]; uint4 v; } cA0, cA1, cB0, cB1;
                cA0.qq[0] = a0q; cA0.qq[1] = a1q;
                cA1.qq[0] = a2q; cA1.qq[1] = a3q;
                cB0.qq[0] = b0q; cB0.qq[1] = b1q;
                cB1.qq[0] = b2q; cB1.qq[1] = b3q;
                char* hwA = (char*)lds_h[0] + grow * 1024;
                *(uint4*)(hwA + ((gcb)      ^ gsw)) = cA0.v;
                *(uint4*)(hwA + ((gcb + 16) ^ gsw)) = cA1.v;
                char* hwB = (char*)lds_h[1] + grow * 1024;
                *(uint4*)(hwB + ((gcb)      ^ gsw)) = cB0.v;
                *(uint4*)(hwB + ((gcb + 16) ^ gsw)) = cB1.v;
                if (q == (int)(t & 3)) {
                    unsigned short* hrA = hs + ((size_t)(r0A + grow) * T_ + t) * H_ + (tid & 31) * 16;
                    ((uint4*)hrA)[0] = cA0.v;
                    ((uint4*)hrA)[1] = cA1.v;
                    unsigned short* hrB = hs + ((size_t)(r0B + grow) * T_ + t) * H_ + (tid & 31) * 16;
                    ((uint4*)hrB)[0] = cB0.v;
                    ((uint4*)hrB)[1] = cB1.v;
                }
            }
            asm volatile("s_waitcnt lgkmcnt(0)" ::: "memory");
            __builtin_amdgcn_s_barrier();
        }
    }

    // tail: hs[:, T-1] scattered from final registers + h_final (fp32)
    {
        const size_t tb = (size_t)(T_ - 1) * H_;
        hs[(size_t)(xrA + 0) * (T_ * H_) + tb + n] = (unsigned short)mA0;
        hs[(size_t)(xrA + 1) * (T_ * H_) + tb + n] = (unsigned short)mA1;
        hs[(size_t)(xrA + 2) * (T_ * H_) + tb + n] = (unsigned short)mA2;
        hs[(size_t)(xrA + 3) * (T_ * H_) + tb + n] = (unsigned short)mA3;
        hs[(size_t)(xrB + 0) * (T_ * H_) + tb + n] = (unsigned short)mB0;
        hs[(size_t)(xrB + 1) * (T_ * H_) + tb + n] = (unsigned short)mB1;
        hs[(size_t)(xrB + 2) * (T_ * H_) + tb + n] = (unsigned short)mB2;
        hs[(size_t)(xrB + 3) * (T_ * H_) + tb + n] = (unsigned short)mB3;
        float* hfin = out + (size_t)B_ * T_ * O_;
        hfin[(xrA + 0) * H_ + n] = bf2f((unsigned short)mA0);
        hfin[(xrA + 1) * H_ + n] = bf2f((unsigned short)mA1);
        hfin[(xrA + 2) * H_ + n] = bf2f((unsigned short)mA2);
        hfin[(xrA + 3) * H_ + n] = bf2f((unsigned short)mA3);
        hfin[(xrB + 0) * H_ + n] = bf2f((unsigned short)mB0);
        hfin[(xrB + 1) * H_ + n] = bf2f((unsigned short)mB1);
        hfin[(xrB + 2) * H_ + n] = bf2f((unsigned short)mB2);
        hfin[(xrB + 3) * H_ + n] = bf2f((unsigned short)mB3);
    }
}

// ---------------- K3: outputs = hs @ Wd^T + bd, in-place over hs slots ----------------
__launch_bounds__(512, 2)
__global__ void k_out(const float* __restrict__ bd, float* out) {
    int tid = threadIdx.x;
    int w = tid >> 6, l = tid & 63;
    int hi = l >> 4, lo = l & 15;
    size_t m0 = (size_t)blockIdx.x * 256 + w * 32;
    const unsigned short* hsb = (const unsigned short*)out;
    float bdv[16];
#pragma unroll
    for (int nt = 0; nt < 16; nt++) bdv[nt] = bd[nt * 16 + lo];
    f32x4 acc[2][16];
#pragma unroll
    for (int m = 0; m < 2; m++)
#pragma unroll
        for (int nt = 0; nt < 16; nt++) { acc[m][nt][0] = 0.f; acc[m][nt][1] = 0.f; acc[m][nt][2] = 0.f; acc[m][nt][3] = 0.f; }
#pragma unroll 2
    for (int kt = 0; kt < 16; kt++) {
        bf16x8 a0 = *(const bf16x8*)(hsb + (m0 + lo) * 512 + kt * 32 + hi * 8);
        bf16x8 a1 = *(const bf16x8*)(hsb + (m0 + 16 + lo) * 512 + kt * 32 + hi * 8);
#pragma unroll
        for (int nt = 0; nt < 16; nt++) {
            bf16x8 bf = *(const bf16x8*)(g_Wdf + (size_t)(nt * 16 + kt) * 512 + l * 8);
            acc[0][nt] = __builtin_amdgcn_mfma_f32_16x16x32_bf16(a0, bf, acc[0][nt], 0, 0, 0);
            acc[1][nt] = __builtin_amdgcn_mfma_f32_16x16x32_bf16(a1, bf, acc[1][nt], 0, 0, 0);
        }
    }
#pragma unroll
    for (int m = 0; m < 2; m++)
#pragma unroll
        for (int nt = 0; nt < 16; nt++)
#pragma unroll
            for (int rg = 0; rg < 4; rg++) {
                size_t row = m0 + m * 16 + hi * 4 + rg;
                out[row * O_ + nt * 16 + lo] = acc[m][nt][rg] + bdv[nt];
            }
}

extern "C" void kernel_launch(void* const* d_in, const int* in_sizes, int n_in,
                              void* d_out, int out_size, void* d_ws, size_t ws_size,
                              hipStream_t stream) {
    const int*   x   = (const int*)d_in[0];
    const float* h0  = (const float*)d_in[1];
    const float* emb = (const float*)d_in[2];
    const float* W   = (const float*)d_in[3];
    const float* b   = (const float*)d_in[4];
    const float* Wd  = (const float*)d_in[5];
    const float* bd  = (const float*)d_in[6];
    float* out = (float*)d_out;

    k_embWx<<<dim3(V_), dim3(256), 0, stream>>>(emb, W, b);
    k_fragWh<<<dim3(128), dim3(256), 0, stream>>>(W);
    k_fragWd<<<dim3(64), dim3(256), 0, stream>>>(Wd);
    k_rnn<<<dim3(32), dim3(512), 0, stream>>>(x, h0, out);
    k_out<<<dim3(1024), dim3(512), 0, stream>>>(bd, out);
}